// Round 3
// baseline (293.854 us; speedup 1.0000x reference)
//
#include <hip/hip_runtime.h>
#include <hip/hip_bf16.h>

#define MROWS 8192   // N*T
#define KDIM  512    // CIN
#define NCOL  8192   // codebook size K
#define TSEQ  2048
#define NT    8      // K-tiles (KDIM/64)

typedef float f32x4 __attribute__((ext_vector_type(4)));
typedef __bf16 bf16x8 __attribute__((ext_vector_type(8)));

__device__ __forceinline__ unsigned short f2bf(float x) {
  unsigned int u = __float_as_uint(x);
  u += 0x7fffu + ((u >> 16) & 1u);
  return (unsigned short)(u >> 16);
}

// ---------------- conversions ----------------
__global__ void convA_kernel(const float* __restrict__ X, unsigned short* __restrict__ Y) {
  int i = blockIdx.x * 256 + threadIdx.x;
  float4 v = reinterpret_cast<const float4*>(X)[i];
  ushort4 o;
  o.x = f2bf(v.x); o.y = f2bf(v.y); o.z = f2bf(v.z); o.w = f2bf(v.w);
  reinterpret_cast<ushort4*>(Y)[i] = o;
}

__global__ void convB_kernel(const float* __restrict__ W, unsigned short* __restrict__ Bt) {
  __shared__ float tile[32][33];
  int bx = blockIdx.x, by = blockIdx.y;
  int tx = threadIdx.x, ty = threadIdx.y;
  #pragma unroll
  for (int i = 0; i < 32; i += 8)
    tile[ty + i][tx] = W[(size_t)(by * 32 + ty + i) * NCOL + bx * 32 + tx];
  __syncthreads();
  #pragma unroll
  for (int i = 0; i < 32; i += 8)
    Bt[(size_t)(bx * 32 + ty + i) * KDIM + by * 32 + tx] = f2bf(tile[tx][ty + i]);
}

// ---------------- f = normalize(feats @ proj) ----------------
__global__ void fproj_kernel(const float* __restrict__ feats, const float* __restrict__ proj,
                             float* __restrict__ fnorm) {
  int tid = threadIdx.x;
  int rl = tid >> 4, d = tid & 15;
  int row = blockIdx.x * 16 + rl;
  const float* fr = feats + (size_t)row * KDIM;
  float acc = 0.f;
  #pragma unroll 8
  for (int k = 0; k < KDIM; ++k) acc += fr[k] * proj[k * 16 + d];
  float s = acc * acc;
  #pragma unroll
  for (int o = 1; o < 16; o <<= 1) s += __shfl_xor(s, o);
  float nrm = sqrtf(s);
  fnorm[(size_t)row * 16 + d] = acc / fmaxf(nrm, 1e-12f);
}

// ---------------- nearest codebook (partials, cc fused) ----------------
#define CB_CODES 128
__global__ __launch_bounds__(256)
void targets_part_kernel(const float* __restrict__ fnorm, const float* __restrict__ cb,
                         float* __restrict__ pval, int* __restrict__ pidx) {
  __shared__ float csh[CB_CODES][16];
  __shared__ float ccsh[CB_CODES];
  const int tid = threadIdx.x;
  const int r0 = blockIdx.x * 512 + tid;
  const int r1 = r0 + 256;
  const int c0 = blockIdx.y * CB_CODES;

  {
    int ci = tid >> 1, half = tid & 1;
    const float4* src = reinterpret_cast<const float4*>(cb + (size_t)(c0 + ci) * 16 + half * 8);
    float4 v0 = src[0], v1 = src[1];
    float4* dst = reinterpret_cast<float4*>(&csh[ci][half * 8]);
    dst[0] = v0; dst[1] = v1;
    if (tid < CB_CODES) {  // |c|^2 from global (no extra sync needed)
      const float4* p = reinterpret_cast<const float4*>(cb + (size_t)(c0 + tid) * 16);
      float4 a = p[0], b = p[1], d = p[2], e = p[3];
      ccsh[tid] = a.x*a.x + a.y*a.y + a.z*a.z + a.w*a.w
                + b.x*b.x + b.y*b.y + b.z*b.z + b.w*b.w
                + d.x*d.x + d.y*d.y + d.z*d.z + d.w*d.w
                + e.x*e.x + e.y*e.y + e.z*e.z + e.w*e.w;
    }
  }
  const float4* fp0 = reinterpret_cast<const float4*>(fnorm + (size_t)r0 * 16);
  const float4* fp1 = reinterpret_cast<const float4*>(fnorm + (size_t)r1 * 16);
  float4 a0 = fp0[0], a1 = fp0[1], a2 = fp0[2], a3 = fp0[3];
  float4 b0 = fp1[0], b1 = fp1[1], b2 = fp1[2], b3 = fp1[3];
  __syncthreads();

  float bestA = 3.4e38f, bestB = 3.4e38f;
  int idxA = 0, idxB = 0;
  #pragma unroll 4
  for (int ci = 0; ci < CB_CODES; ++ci) {
    const float4* cvp = reinterpret_cast<const float4*>(&csh[ci][0]);
    float4 c0v = cvp[0], c1v = cvp[1], c2v = cvp[2], c3v = cvp[3];
    float ccv = ccsh[ci];
    float dotA = a0.x*c0v.x + a0.y*c0v.y + a0.z*c0v.z + a0.w*c0v.w
               + a1.x*c1v.x + a1.y*c1v.y + a1.z*c1v.z + a1.w*c1v.w
               + a2.x*c2v.x + a2.y*c2v.y + a2.z*c2v.z + a2.w*c2v.w
               + a3.x*c3v.x + a3.y*c3v.y + a3.z*c3v.z + a3.w*c3v.w;
    float dotB = b0.x*c0v.x + b0.y*c0v.y + b0.z*c0v.z + b0.w*c0v.w
               + b1.x*c1v.x + b1.y*c1v.y + b1.z*c1v.z + b1.w*c1v.w
               + b2.x*c2v.x + b2.y*c2v.y + b2.z*c2v.z + b2.w*c2v.w
               + b3.x*c3v.x + b3.y*c3v.y + b3.z*c3v.z + b3.w*c3v.w;
    float dA = fmaf(-2.f, dotA, ccv);
    float dB = fmaf(-2.f, dotB, ccv);
    if (dA < bestA) { bestA = dA; idxA = c0 + ci; }
    if (dB < bestB) { bestB = dB; idxB = c0 + ci; }
  }
  pval[(size_t)blockIdx.y * MROWS + r0] = bestA;
  pidx[(size_t)blockIdx.y * MROWS + r0] = idxA;
  pval[(size_t)blockIdx.y * MROWS + r1] = bestB;
  pidx[(size_t)blockIdx.y * MROWS + r1] = idxB;
}

__global__ void merge_targets_kernel(const float* __restrict__ pval, const int* __restrict__ pidx,
                                     int* __restrict__ targets) {
  int row = blockIdx.x * 256 + threadIdx.x;
  float best = pval[row]; int bi = pidx[row];
  #pragma unroll 8
  for (int b = 1; b < 64; ++b) {
    float v = pval[(size_t)b * MROWS + row];
    int   i = pidx[(size_t)b * MROWS + row];
    if (v < best) { best = v; bi = i; }
  }
  targets[row] = bi;
}

__global__ void zero_kernel(float* __restrict__ p) {
  p[blockIdx.x * 256 + threadIdx.x] = 0.f;
}

// ================= 256x256 8-phase GEMM + fused CE =================
// LDS: A dbuf 2x32KB @0, B dbuf 2x32KB @65536. Tile 256x256, BK=64.
// A storage: [h(2)][wr(2)][64rows][8slots*16B], tile_row = wr*128 + h*64 + rr
// B storage: [h(2)][wc(4)][32rows][8slots*16B], tile_col = wc*64 + h*32 + rr
// Swizzle: LDS slot s at row rr holds logical slot s ^ (rr&7) (16B slots).

__device__ __forceinline__ void gld16(const void* g, void* l3) {
  __builtin_amdgcn_global_load_lds((const __attribute__((address_space(1))) void*)g,
                                   (__attribute__((address_space(3))) void*)l3, 16, 0, 0);
}

__device__ __forceinline__ void stageA(const unsigned short* __restrict__ A, int row0, int t,
                                       int h, int w, int l, unsigned char* sm) {
  const int p = t & 1, kt = t * 64;
  const int l8 = l >> 3, l7 = l & 7;
  const int cole = kt + ((l7 ^ l8) << 3);               // pre-swizzled source col
  const int rb = row0 + h * 64 + w * 8 + l8;
  unsigned char* d = sm + p * 32768 + h * 16384 + w * 1024;  // wave-uniform dest
  gld16(A + (size_t)rb * KDIM + cole, d);
  gld16(A + (size_t)(rb + 128) * KDIM + cole, d + 8192);
}

__device__ __forceinline__ void stageB(const unsigned short* __restrict__ B, int col0, int t,
                                       int h, int w, int l, unsigned char* sm) {
  const int p = t & 1, kt = t * 64;
  const int l8 = l >> 3, l7 = l & 7;
  const int cole = kt + ((l7 ^ l8) << 3);
  const int w2 = w >> 2, w3 = w & 3;
  #pragma unroll
  for (int i = 0; i < 2; ++i) {
    const int wcs = i * 2 + w2;
    unsigned char* d = sm + 65536 + p * 32768 + h * 16384 + wcs * 4096 + w3 * 1024;
    const int br = col0 + wcs * 64 + h * 32 + w3 * 8 + l8;
    gld16(B + (size_t)br * KDIM + cole, d);
  }
}

#define MFMA_BF16 __builtin_amdgcn_mfma_f32_16x16x32_bf16

template<bool SNB1, bool SN2, int ENDVM>
__device__ __forceinline__ void do_tile(const unsigned short* __restrict__ A,
                                        const unsigned short* __restrict__ B,
                                        unsigned char* sm, int t, int row0, int col0,
                                        int w, int l, int wr, int wc, f32x4 (&acc)[8][4]) {
  const int p = t & 1;
  const int l7 = l & 7, l15 = l & 15, l16 = l >> 4;
  const int colx0 = ((l16) ^ l7) * 16;         // ks=0 swizzled slot
  const int colx1 = ((4 + l16) ^ l7) * 16;     // ks=1
  const int abase = p * 32768 + wr * 8192 + l15 * 128;
  const int bbase = 65536 + p * 32768 + wc * 4096 + l15 * 128;
  bf16x8 af[4][2], bfr[4][2];

  // ---- phase 0: read A(mi0-3) + B(ni0-1); stage T+1.B-H1; mfma q(0,0)
  #pragma unroll
  for (int mi = 0; mi < 4; ++mi) {
    af[mi][0] = *(const bf16x8*)(sm + abase + mi * 2048 + colx0);
    af[mi][1] = *(const bf16x8*)(sm + abase + mi * 2048 + colx1);
  }
  #pragma unroll
  for (int ni = 0; ni < 2; ++ni) {
    bfr[ni][0] = *(const bf16x8*)(sm + bbase + ni * 2048 + colx0);
    bfr[ni][1] = *(const bf16x8*)(sm + bbase + ni * 2048 + colx1);
  }
  if (SNB1) stageB(B, col0, t + 1, 1, w, l, sm);
  __builtin_amdgcn_s_barrier();
  __builtin_amdgcn_s_setprio(1);
  #pragma unroll
  for (int mi = 0; mi < 4; ++mi)
    #pragma unroll
    for (int ni = 0; ni < 2; ++ni) {
      acc[mi][ni] = MFMA_BF16(af[mi][0], bfr[ni][0], acc[mi][ni], 0, 0, 0);
      acc[mi][ni] = MFMA_BF16(af[mi][1], bfr[ni][1], acc[mi][ni], 0, 0, 0);
    }
  __builtin_amdgcn_s_setprio(0);
  __builtin_amdgcn_s_barrier();

  // ---- phase 1: read B(ni2-3); stage T+2.A-H0; mfma q(0,1)
  #pragma unroll
  for (int ni = 2; ni < 4; ++ni) {
    bfr[ni][0] = *(const bf16x8*)(sm + bbase + 16384 + (ni - 2) * 2048 + colx0);
    bfr[ni][1] = *(const bf16x8*)(sm + bbase + 16384 + (ni - 2) * 2048 + colx1);
  }
  if (SN2) stageA(A, row0, t + 2, 0, w, l, sm);
  __builtin_amdgcn_s_barrier();
  __builtin_amdgcn_s_setprio(1);
  #pragma unroll
  for (int mi = 0; mi < 4; ++mi)
    #pragma unroll
    for (int ni = 2; ni < 4; ++ni) {
      acc[mi][ni] = MFMA_BF16(af[mi][0], bfr[ni][0], acc[mi][ni], 0, 0, 0);
      acc[mi][ni] = MFMA_BF16(af[mi][1], bfr[ni][1], acc[mi][ni], 0, 0, 0);
    }
  __builtin_amdgcn_s_setprio(0);
  __builtin_amdgcn_s_barrier();

  // ---- phase 2: read A(mi4-7); stage T+2.B-H0; mfma q(1,0)
  #pragma unroll
  for (int mi = 0; mi < 4; ++mi) {
    af[mi][0] = *(const bf16x8*)(sm + abase + 16384 + mi * 2048 + colx0);
    af[mi][1] = *(const bf16x8*)(sm + abase + 16384 + mi * 2048 + colx1);
  }
  if (SN2) stageB(B, col0, t + 2, 0, w, l, sm);
  __builtin_amdgcn_s_barrier();
  __builtin_amdgcn_s_setprio(1);
  #pragma unroll
  for (int mi = 0; mi < 4; ++mi)
    #pragma unroll
    for (int ni = 0; ni < 2; ++ni) {
      acc[4 + mi][ni] = MFMA_BF16(af[mi][0], bfr[ni][0], acc[4 + mi][ni], 0, 0, 0);
      acc[4 + mi][ni] = MFMA_BF16(af[mi][1], bfr[ni][1], acc[4 + mi][ni], 0, 0, 0);
    }
  __builtin_amdgcn_s_setprio(0);
  __builtin_amdgcn_s_barrier();

  // ---- phase 3: stage T+2.A-H1; mfma q(1,1); end-of-tile vmcnt
  if (SN2) stageA(A, row0, t + 2, 1, w, l, sm);
  __builtin_amdgcn_s_barrier();
  __builtin_amdgcn_s_setprio(1);
  #pragma unroll
  for (int mi = 0; mi < 4; ++mi)
    #pragma unroll
    for (int ni = 2; ni < 4; ++ni) {
      acc[4 + mi][ni] = MFMA_BF16(af[mi][0], bfr[ni][0], acc[4 + mi][ni], 0, 0, 0);
      acc[4 + mi][ni] = MFMA_BF16(af[mi][1], bfr[ni][1], acc[4 + mi][ni], 0, 0, 0);
    }
  __builtin_amdgcn_s_setprio(0);
  if (ENDVM == 6) asm volatile("s_waitcnt vmcnt(6)" ::: "memory");
  else if (ENDVM == 0) asm volatile("s_waitcnt vmcnt(0)" ::: "memory");
  __builtin_amdgcn_s_barrier();
}

__global__ __launch_bounds__(512, 2)
void gemm_ce_kernel(const unsigned short* __restrict__ A,  // [MROWS][KDIM] bf16
                    const unsigned short* __restrict__ B,  // [NCOL][KDIM] bf16 (W^T)
                    const float* __restrict__ bias,
                    const int* __restrict__ targets,
                    float* __restrict__ rowsum,
                    float* __restrict__ tgtlog) {
  __shared__ __align__(128) unsigned char sm[131072];
  const int tid = threadIdx.x;
  const int w = tid >> 6, l = tid & 63;
  const int wr = w >> 2, wc = w & 3;
  const int bid = blockIdx.x;
  const int swz = (bid & 7) * 128 + (bid >> 3);   // XCD swizzle (1024 % 8 == 0)
  const int bx = swz & 31, by = swz >> 5;
  const int row0 = by * 256, col0 = bx * 256;

  f32x4 acc[8][4];
  #pragma unroll
  for (int i = 0; i < 8; ++i)
    #pragma unroll
    for (int j = 0; j < 4; ++j) acc[i][j] = (f32x4){0.f, 0.f, 0.f, 0.f};

  // prologue: T0 fully + T1.{A0,B0,A1}; wait T0 landed (3 HT in flight)
  stageA(A, row0, 0, 0, w, l, sm); stageB(B, col0, 0, 0, w, l, sm);
  stageA(A, row0, 0, 1, w, l, sm); stageB(B, col0, 0, 1, w, l, sm);
  stageA(A, row0, 1, 0, w, l, sm); stageB(B, col0, 1, 0, w, l, sm);
  stageA(A, row0, 1, 1, w, l, sm);
  asm volatile("s_waitcnt vmcnt(6)" ::: "memory");
  __builtin_amdgcn_s_barrier();

  #pragma unroll 2
  for (int t = 0; t < 6; ++t)
    do_tile<true, true, 6>(A, B, sm, t, row0, col0, w, l, wr, wc, acc);
  do_tile<true, false, 0>(A, B, sm, 6, row0, col0, w, l, wr, wc, acc);
  do_tile<false, false, -1>(A, B, sm, 7, row0, col0, w, l, wr, wc, acc);

  // fused CE epilogue
  const int l15 = l & 15, l16 = l >> 4;
  float bv[4]; int cols[4];
  #pragma unroll
  for (int ni = 0; ni < 4; ++ni) {
    cols[ni] = col0 + wc * 64 + ni * 16 + l15;
    bv[ni] = bias[cols[ni]];
  }
  #pragma unroll
  for (int mi = 0; mi < 8; ++mi) {
    int rbase = row0 + wr * 128 + mi * 16 + l16 * 4;
    #pragma unroll
    for (int j = 0; j < 4; ++j) {
      int r = rbase + j;
      int tg = targets[r];
      float se = 0.f;
      #pragma unroll
      for (int ni = 0; ni < 4; ++ni) {
        float lg = acc[mi][ni][j] + bv[ni];
        se += __expf(lg);
        if (cols[ni] == tg) atomicAdd(&tgtlog[r], lg);
      }
      #pragma unroll
      for (int o = 1; o < 16; o <<= 1) se += __shfl_xor(se, o);
      if (l15 == 0) atomicAdd(&rowsum[r], se);
    }
  }
}

// ---------------- final masked-mean loss ----------------
__global__ void loss_kernel(const float* __restrict__ rowsum, const float* __restrict__ tgtl,
                            const int* __restrict__ lens, float* __restrict__ out) {
  __shared__ float sh[256];
  __shared__ int shc[256];
  int tid = threadIdx.x;
  float s = 0.f; int c = 0;
  for (int r = tid; r < MROWS; r += 256) {
    int n = r >> 11;
    int t = r & (TSEQ - 1);
    if (t < lens[n]) { s += logf(rowsum[r]) - tgtl[r]; c++; }
  }
  sh[tid] = s; shc[tid] = c;
  __syncthreads();
  for (int o = 128; o > 0; o >>= 1) {
    if (tid < o) { sh[tid] += sh[tid + o]; shc[tid] += shc[tid + o]; }
    __syncthreads();
  }
  if (tid == 0) out[0] = sh[0] / (float)max(shc[0], 1);
}

extern "C" void kernel_launch(void* const* d_in, const int* in_sizes, int n_in,
                              void* d_out, int out_size, void* d_ws, size_t ws_size,
                              hipStream_t stream) {
  const float* feats    = (const float*)d_in[0];
  const float* context  = (const float*)d_in[1];
  const int*   lens     = (const int*)d_in[2];
  const float* proj     = (const float*)d_in[3];
  const float* codebook = (const float*)d_in[4];
  const float* W_enc    = (const float*)d_in[5];
  const float* b_enc    = (const float*)d_in[6];
  float* out = (float*)d_out;

  char* ws = (char*)d_ws;
  float* pval    = (float*)(ws);                               // 2 MB (aliases Abf)
  int*   pidx    = (int*)  (ws + 2097152);                     // 2 MB
  unsigned short* Abf = (unsigned short*)(ws);                 // 8 MB
  unsigned short* Bbf = (unsigned short*)(ws + 8388608);       // 8 MB
  float* fnorm   = (float*)(ws + 16777216);                    // 512 KB
  float* rowsum  = (float*)(ws + 17334272);                    // 32 KB
  float* tgtlog  = (float*)(ws + 17367040);                    // 32 KB (contiguous with rowsum)
  int*   targets = (int*)  (ws + 17399808);                    // 32 KB

  // --- targets first (pval/pidx alias the Abf region) ---
  fproj_kernel<<<MROWS / 16, 256, 0, stream>>>(feats, proj, fnorm);
  {
    dim3 g(MROWS / 512, NCOL / CB_CODES);   // (16, 64)
    targets_part_kernel<<<g, 256, 0, stream>>>(fnorm, codebook, pval, pidx);
  }
  merge_targets_kernel<<<MROWS / 256, 256, 0, stream>>>(pval, pidx, targets);

  // --- conversions (safe to overwrite pval/pidx now) ---
  convA_kernel<<<MROWS * KDIM / 4 / 256, 256, 0, stream>>>(context, Abf);
  {
    dim3 g(NCOL / 32, KDIM / 32), b(32, 8);
    convB_kernel<<<g, b, 0, stream>>>(W_enc, Bbf);
  }

  // --- fused GEMM + CE ---
  zero_kernel<<<64, 256, 0, stream>>>(rowsum);   // rowsum+tgtlog contiguous
  gemm_ce_kernel<<<1024, 512, 0, stream>>>(Abf, Bbf, b_enc, targets, rowsum, tgtlog);
  loss_kernel<<<1, 256, 0, stream>>>(rowsum, tgtlog, lens, out);
}